// Round 1
// baseline (8842.262 us; speedup 1.0000x reference)
//
#include <hip/hip_runtime.h>

#define TPB 256

// Hardware fp32 atomic (global_atomic_add_f32) — avoids CAS-loop fallback.
__device__ __forceinline__ void atomAddF(float* p, float v) {
    unsafeAtomicAdd(p, v);
}

// ---- degree count: deg[d] += 1 for every edge destination ----
__global__ __launch_bounds__(TPB) void k_degree(const int* __restrict__ dst,
                                                int* __restrict__ deg, int E) {
    int e4 = E >> 2;
    int i = blockIdx.x * TPB + threadIdx.x;
    if (i < e4) {
        int4 d = ((const int4*)dst)[i];
        atomicAdd(&deg[d.x], 1);
        atomicAdd(&deg[d.y], 1);
        atomicAdd(&deg[d.z], 1);
        atomicAdd(&deg[d.w], 1);
    }
    if (i < (E & 3)) {  // tail (E not multiple of 4)
        atomicAdd(&deg[dst[(e4 << 2) + i]], 1);
    }
}

// ---- dinv[i] = rsqrt(deg[i] + 1)   (+1 = self-loop) ----
__global__ __launch_bounds__(TPB) void k_dinv(const int* __restrict__ deg,
                                              float* __restrict__ dinv, int n) {
    int i = blockIdx.x * TPB + threadIdx.x;
    if (i >= n) return;
    dinv[i] = rsqrtf((float)(deg[i] + 1));
}

// ---- layer 1 transform: hs = dinv * (x @ W1); acc init = hs (self-loop) ----
// 32 lanes per node, each lane loads a float4 of x and 4 rows of W1.
__global__ __launch_bounds__(TPB) void k_xform1(const float* __restrict__ x,
                                                const float* __restrict__ W,
                                                const float* __restrict__ dinv,
                                                float* __restrict__ hs,
                                                float* __restrict__ acc, int n) {
    int node = blockIdx.x * (TPB / 32) + (threadIdx.x >> 5);
    int lane = threadIdx.x & 31;
    if (node >= n) return;
    int k = lane * 4;
    float4 xv = *(const float4*)(x + (size_t)node * 128 + k);
    float4 w0 = *(const float4*)(W + (size_t)(k + 0) * 4);
    float4 w1 = *(const float4*)(W + (size_t)(k + 1) * 4);
    float4 w2 = *(const float4*)(W + (size_t)(k + 2) * 4);
    float4 w3 = *(const float4*)(W + (size_t)(k + 3) * 4);
    float p0 = xv.x * w0.x + xv.y * w1.x + xv.z * w2.x + xv.w * w3.x;
    float p1 = xv.x * w0.y + xv.y * w1.y + xv.z * w2.y + xv.w * w3.y;
    float p2 = xv.x * w0.z + xv.y * w1.z + xv.z * w2.z + xv.w * w3.z;
    float p3 = xv.x * w0.w + xv.y * w1.w + xv.z * w2.w + xv.w * w3.w;
#pragma unroll
    for (int off = 16; off >= 1; off >>= 1) {
        p0 += __shfl_down(p0, off, 32);
        p1 += __shfl_down(p1, off, 32);
        p2 += __shfl_down(p2, off, 32);
        p3 += __shfl_down(p3, off, 32);
    }
    if (lane == 0) {
        float dv = dinv[node];
        float4 r = make_float4(dv * p0, dv * p1, dv * p2, dv * p3);
        *(float4*)(hs + (size_t)node * 4)  = r;
        *(float4*)(acc + (size_t)node * 4) = r;
    }
}

// ---- edge scatter, 4-wide features: acc[dst] += hs[src] ----
__global__ __launch_bounds__(TPB) void k_scatter4(const int* __restrict__ src,
                                                  const int* __restrict__ dst,
                                                  const float* __restrict__ hs,
                                                  float* __restrict__ acc, int E) {
    int e4 = E >> 2;
    int i = blockIdx.x * TPB + threadIdx.x;
    if (i < e4) {
        int4 s = ((const int4*)src)[i];
        int4 d = ((const int4*)dst)[i];
        float4 v0 = *(const float4*)(hs + (size_t)s.x * 4);
        float4 v1 = *(const float4*)(hs + (size_t)s.y * 4);
        float4 v2 = *(const float4*)(hs + (size_t)s.z * 4);
        float4 v3 = *(const float4*)(hs + (size_t)s.w * 4);
        float* a;
        a = acc + (size_t)d.x * 4;
        atomAddF(a + 0, v0.x); atomAddF(a + 1, v0.y); atomAddF(a + 2, v0.z); atomAddF(a + 3, v0.w);
        a = acc + (size_t)d.y * 4;
        atomAddF(a + 0, v1.x); atomAddF(a + 1, v1.y); atomAddF(a + 2, v1.z); atomAddF(a + 3, v1.w);
        a = acc + (size_t)d.z * 4;
        atomAddF(a + 0, v2.x); atomAddF(a + 1, v2.y); atomAddF(a + 2, v2.z); atomAddF(a + 3, v2.w);
        a = acc + (size_t)d.w * 4;
        atomAddF(a + 0, v3.x); atomAddF(a + 1, v3.y); atomAddF(a + 2, v3.z); atomAddF(a + 3, v3.w);
    }
    if (i < (E & 3)) {
        int e = (e4 << 2) + i;
        int s = src[e], d = dst[e];
        float4 v = *(const float4*)(hs + (size_t)s * 4);
        float* a = acc + (size_t)d * 4;
        atomAddF(a + 0, v.x); atomAddF(a + 1, v.y); atomAddF(a + 2, v.z); atomAddF(a + 3, v.w);
    }
}

// ---- edge scatter, 2-wide features (layer 3) ----
__global__ __launch_bounds__(TPB) void k_scatter2(const int* __restrict__ src,
                                                  const int* __restrict__ dst,
                                                  const float* __restrict__ hs,
                                                  float* __restrict__ acc, int E) {
    int e4 = E >> 2;
    int i = blockIdx.x * TPB + threadIdx.x;
    if (i < e4) {
        int4 s = ((const int4*)src)[i];
        int4 d = ((const int4*)dst)[i];
        float2 v0 = *(const float2*)(hs + (size_t)s.x * 2);
        float2 v1 = *(const float2*)(hs + (size_t)s.y * 2);
        float2 v2 = *(const float2*)(hs + (size_t)s.z * 2);
        float2 v3 = *(const float2*)(hs + (size_t)s.w * 2);
        float* a;
        a = acc + (size_t)d.x * 2; atomAddF(a + 0, v0.x); atomAddF(a + 1, v0.y);
        a = acc + (size_t)d.y * 2; atomAddF(a + 0, v1.x); atomAddF(a + 1, v1.y);
        a = acc + (size_t)d.z * 2; atomAddF(a + 0, v2.x); atomAddF(a + 1, v2.y);
        a = acc + (size_t)d.w * 2; atomAddF(a + 0, v3.x); atomAddF(a + 1, v3.y);
    }
    if (i < (E & 3)) {
        int e = (e4 << 2) + i;
        int s = src[e], d = dst[e];
        float2 v = *(const float2*)(hs + (size_t)s * 2);
        float* a = acc + (size_t)d * 2;
        atomAddF(a + 0, v.x); atomAddF(a + 1, v.y);
    }
}

// ---- layer 2 transform: in = relu(dinv*acc1 + b1); hs2 = dinv*(in @ W2); acc2 = hs2 ----
__global__ __launch_bounds__(TPB) void k_xform2(const float* __restrict__ acc_in,
                                                const float* __restrict__ dinv,
                                                const float* __restrict__ W,
                                                const float* __restrict__ b,
                                                float* __restrict__ hs,
                                                float* __restrict__ acc, int n) {
    int i = blockIdx.x * TPB + threadIdx.x;
    if (i >= n) return;
    float dv = dinv[i];
    float4 a = *(const float4*)(acc_in + (size_t)i * 4);
    float h0 = fmaxf(fmaf(dv, a.x, b[0]), 0.f);
    float h1 = fmaxf(fmaf(dv, a.y, b[1]), 0.f);
    float h2 = fmaxf(fmaf(dv, a.z, b[2]), 0.f);
    float h3 = fmaxf(fmaf(dv, a.w, b[3]), 0.f);
    float4 r;
    r.x = dv * (h0 * W[0] + h1 * W[4] + h2 * W[8]  + h3 * W[12]);
    r.y = dv * (h0 * W[1] + h1 * W[5] + h2 * W[9]  + h3 * W[13]);
    r.z = dv * (h0 * W[2] + h1 * W[6] + h2 * W[10] + h3 * W[14]);
    r.w = dv * (h0 * W[3] + h1 * W[7] + h2 * W[11] + h3 * W[15]);
    *(float4*)(hs + (size_t)i * 4)  = r;
    *(float4*)(acc + (size_t)i * 4) = r;
}

// ---- layer 3 transform: in = relu(dinv*acc2 + b2); hs3 = dinv*(in @ W3) [Fout=2] ----
__global__ __launch_bounds__(TPB) void k_xform3(const float* __restrict__ acc_in,
                                                const float* __restrict__ dinv,
                                                const float* __restrict__ W,
                                                const float* __restrict__ b,
                                                float* __restrict__ hs,
                                                float* __restrict__ acc, int n) {
    int i = blockIdx.x * TPB + threadIdx.x;
    if (i >= n) return;
    float dv = dinv[i];
    float4 a = *(const float4*)(acc_in + (size_t)i * 4);
    float h0 = fmaxf(fmaf(dv, a.x, b[0]), 0.f);
    float h1 = fmaxf(fmaf(dv, a.y, b[1]), 0.f);
    float h2 = fmaxf(fmaf(dv, a.z, b[2]), 0.f);
    float h3 = fmaxf(fmaf(dv, a.w, b[3]), 0.f);
    float2 r;
    r.x = dv * (h0 * W[0] + h1 * W[2] + h2 * W[4] + h3 * W[6]);
    r.y = dv * (h0 * W[1] + h1 * W[3] + h2 * W[5] + h3 * W[7]);
    *(float2*)(hs + (size_t)i * 2)  = r;
    *(float2*)(acc + (size_t)i * 2) = r;
}

// ---- final epilogue: out = dinv*acc3 + b3 (no relu) ----
__global__ __launch_bounds__(TPB) void k_final(const float* __restrict__ acc_in,
                                               const float* __restrict__ dinv,
                                               const float* __restrict__ b,
                                               float* __restrict__ out, int n) {
    int i = blockIdx.x * TPB + threadIdx.x;
    if (i >= n) return;
    float dv = dinv[i];
    float2 a = *(const float2*)(acc_in + (size_t)i * 2);
    float2 o;
    o.x = fmaf(dv, a.x, b[0]);
    o.y = fmaf(dv, a.y, b[1]);
    *(float2*)(out + (size_t)i * 2) = o;
}

extern "C" void kernel_launch(void* const* d_in, const int* in_sizes, int n_in,
                              void* d_out, int out_size, void* d_ws, size_t ws_size,
                              hipStream_t stream) {
    const float* x  = (const float*)d_in[0];
    const int*   ei = (const int*)d_in[1];   // int32 (JAX x64 disabled)
    const float* W1 = (const float*)d_in[2];
    const float* b1 = (const float*)d_in[3];
    const float* W2 = (const float*)d_in[4];
    const float* b2 = (const float*)d_in[5];
    const float* W3 = (const float*)d_in[6];
    const float* b3 = (const float*)d_in[7];
    float* out = (float*)d_out;

    const int n = in_sizes[0] / 128;   // 500000
    const int E = in_sizes[1] / 2;     // 16000000
    const int* src = ei;
    const int* dst = ei + E;

    // workspace layout (poisoned 0xAA every call — deg memset below; acc/hs fully written)
    char* ws = (char*)d_ws;
    size_t off = 0;
    auto alloc = [&](size_t bytes) -> char* {
        char* p = ws + off;
        off += (bytes + 255) & ~(size_t)255;
        return p;
    };
    int*   deg  = (int*)  alloc((size_t)n * 4);
    float* dinv = (float*)alloc((size_t)n * 4);
    float* hs1  = (float*)alloc((size_t)n * 16);
    float* acc1 = (float*)alloc((size_t)n * 16);
    float* hs2  = (float*)alloc((size_t)n * 16);
    float* acc2 = (float*)alloc((size_t)n * 16);
    float* hs3  = (float*)alloc((size_t)n * 8);
    float* acc3 = (float*)alloc((size_t)n * 8);
    (void)ws_size; (void)n_in; (void)out_size;

    hipMemsetAsync(deg, 0, (size_t)n * 4, stream);

    int e4 = E >> 2;
    int gridE = (e4 > 0 ? (e4 + TPB - 1) / TPB : 1);
    int gridN = (n + TPB - 1) / TPB;
    int gridX1 = (n + (TPB / 32) - 1) / (TPB / 32);

    k_degree<<<gridE, TPB, 0, stream>>>(dst, deg, E);
    k_dinv<<<gridN, TPB, 0, stream>>>(deg, dinv, n);

    // layer 1
    k_xform1<<<gridX1, TPB, 0, stream>>>(x, W1, dinv, hs1, acc1, n);
    k_scatter4<<<gridE, TPB, 0, stream>>>(src, dst, hs1, acc1, E);
    // layer 2
    k_xform2<<<gridN, TPB, 0, stream>>>(acc1, dinv, W2, b1, hs2, acc2, n);
    k_scatter4<<<gridE, TPB, 0, stream>>>(src, dst, hs2, acc2, E);
    // layer 3
    k_xform3<<<gridN, TPB, 0, stream>>>(acc2, dinv, W3, b2, hs3, acc3, n);
    k_scatter2<<<gridE, TPB, 0, stream>>>(src, dst, hs3, acc3, E);
    // epilogue
    k_final<<<gridN, TPB, 0, stream>>>(acc3, dinv, b3, out, n);
}

// Round 2
// 1915.705 us; speedup vs baseline: 4.6157x; 4.6157x over previous
//
#include <hip/hip_runtime.h>

#define TPB 256

// Hardware fp32 atomic (global_atomic_add_f32) — avoids CAS-loop fallback.
__device__ __forceinline__ void atomAddF(float* p, float v) {
    unsafeAtomicAdd(p, v);
}

// ============================ shared kernels ============================

// ---- dinv[i] = rsqrt(deg[i] + 1)   (+1 = self-loop) ----
__global__ __launch_bounds__(TPB) void k_dinv(const int* __restrict__ deg,
                                              float* __restrict__ dinv, int n) {
    int i = blockIdx.x * TPB + threadIdx.x;
    if (i >= n) return;
    dinv[i] = rsqrtf((float)(deg[i] + 1));
}

// ---- layer 1 transform: hs = dinv * (x @ W1) ----
// 32 lanes per node, each lane loads a float4 of x and 4 rows of W1.
__global__ __launch_bounds__(TPB) void k_xform1(const float* __restrict__ x,
                                                const float* __restrict__ W,
                                                const float* __restrict__ dinv,
                                                float* __restrict__ hs, int n) {
    int node = blockIdx.x * (TPB / 32) + (threadIdx.x >> 5);
    int lane = threadIdx.x & 31;
    if (node >= n) return;
    int k = lane * 4;
    float4 xv = *(const float4*)(x + (size_t)node * 128 + k);
    float4 w0 = *(const float4*)(W + (size_t)(k + 0) * 4);
    float4 w1 = *(const float4*)(W + (size_t)(k + 1) * 4);
    float4 w2 = *(const float4*)(W + (size_t)(k + 2) * 4);
    float4 w3 = *(const float4*)(W + (size_t)(k + 3) * 4);
    float p0 = xv.x * w0.x + xv.y * w1.x + xv.z * w2.x + xv.w * w3.x;
    float p1 = xv.x * w0.y + xv.y * w1.y + xv.z * w2.y + xv.w * w3.y;
    float p2 = xv.x * w0.z + xv.y * w1.z + xv.z * w2.z + xv.w * w3.z;
    float p3 = xv.x * w0.w + xv.y * w1.w + xv.z * w2.w + xv.w * w3.w;
#pragma unroll
    for (int off = 16; off >= 1; off >>= 1) {
        p0 += __shfl_down(p0, off, 32);
        p1 += __shfl_down(p1, off, 32);
        p2 += __shfl_down(p2, off, 32);
        p3 += __shfl_down(p3, off, 32);
    }
    if (lane == 0) {
        float dv = dinv[node];
        *(float4*)(hs + (size_t)node * 4) = make_float4(dv * p0, dv * p1, dv * p2, dv * p3);
    }
}

// ============================ CSR build ============================

// ---- pass A: pos[e] = arrival order of edge e at its dst; cnt ends as degree ----
__global__ __launch_bounds__(TPB) void k_binpos(const int* __restrict__ dst,
                                                int* __restrict__ cnt,
                                                int* __restrict__ pos, int E) {
    int e4 = E >> 2;
    int i = blockIdx.x * TPB + threadIdx.x;
    if (i < e4) {
        int4 d = ((const int4*)dst)[i];
        int4 p;
        p.x = atomicAdd(&cnt[d.x], 1);
        p.y = atomicAdd(&cnt[d.y], 1);
        p.z = atomicAdd(&cnt[d.z], 1);
        p.w = atomicAdd(&cnt[d.w], 1);
        ((int4*)pos)[i] = p;
    }
    if (i < (E & 3)) {
        int e = (e4 << 2) + i;
        pos[e] = atomicAdd(&cnt[dst[e]], 1);
    }
}

// ---- exclusive scan, two-level (2048 elems/block) ----
#define SCAN_CHUNK 2048
__global__ __launch_bounds__(TPB) void k_scan_block(const int* __restrict__ in,
                                                    int* __restrict__ out,
                                                    int* __restrict__ blockSums, int n) {
    __shared__ int waveTot[TPB / 64];
    int base = blockIdx.x * SCAN_CHUNK + threadIdx.x * 8;
    int v[8];
    int s = 0;
#pragma unroll
    for (int j = 0; j < 8; j++) {
        int idx = base + j;
        int xval = (idx < n) ? in[idx] : 0;
        v[j] = s;
        s += xval;
    }
    int lane = threadIdx.x & 63, wave = threadIdx.x >> 6;
    int t = s;
#pragma unroll
    for (int off = 1; off < 64; off <<= 1) {
        int u = __shfl_up(t, off, 64);
        if (lane >= off) t += u;
    }
    if (lane == 63) waveTot[wave] = t;
    __syncthreads();
    int waveOff = 0;
    for (int w = 0; w < wave; w++) waveOff += waveTot[w];
    int myStart = waveOff + (t - s);  // exclusive over lanes + waves
#pragma unroll
    for (int j = 0; j < 8; j++) {
        int idx = base + j;
        if (idx < n) out[idx] = myStart + v[j];
    }
    if (threadIdx.x == TPB - 1) blockSums[blockIdx.x] = waveOff + t;
}

__global__ __launch_bounds__(TPB) void k_scan_add(int* __restrict__ out,
                                                  const int* __restrict__ blockSums, int n) {
    int i = blockIdx.x * TPB + threadIdx.x;
    if (i >= n) return;
    out[i] += blockSums[i / SCAN_CHUNK];
}

// ---- pass B: perm[row_ptr[dst]+pos] = src ----
__global__ __launch_bounds__(TPB) void k_binfill(const int* __restrict__ src,
                                                 const int* __restrict__ dst,
                                                 const int* __restrict__ pos,
                                                 const int* __restrict__ row_ptr,
                                                 int* __restrict__ perm, int E) {
    int e4 = E >> 2;
    int i = blockIdx.x * TPB + threadIdx.x;
    if (i < e4) {
        int4 s = ((const int4*)src)[i];
        int4 d = ((const int4*)dst)[i];
        int4 p = ((const int4*)pos)[i];
        perm[row_ptr[d.x] + p.x] = s.x;
        perm[row_ptr[d.y] + p.y] = s.y;
        perm[row_ptr[d.z] + p.z] = s.z;
        perm[row_ptr[d.w] + p.w] = s.w;
    }
    if (i < (E & 3)) {
        int e = (e4 << 2) + i;
        perm[row_ptr[dst[e]] + pos[e]] = src[e];
    }
}

// ============================ fused gather layers ============================
// 16 lanes per node; lanes stride the node's in-edge list; shfl_xor reduce.

// layer 1: agg(hs1) -> relu(dv*agg+b1) @ W2 * dv -> hs2 (4-wide in, 4-wide out)
__global__ __launch_bounds__(TPB) void k_gather_l1(const int* __restrict__ row_ptr,
                                                   const int* __restrict__ deg,
                                                   const int* __restrict__ perm,
                                                   const float* __restrict__ hs_in,
                                                   const float* __restrict__ dinv,
                                                   const float* __restrict__ W,
                                                   const float* __restrict__ b,
                                                   float* __restrict__ hs_out, int n) {
    int node = blockIdx.x * (TPB / 16) + (threadIdx.x >> 4);
    int lane = threadIdx.x & 15;
    if (node >= n) return;
    int start = row_ptr[node];
    int d = deg[node];
    float4 s = make_float4(0.f, 0.f, 0.f, 0.f);
    for (int j = lane; j < d; j += 16) {
        int u = perm[start + j];
        float4 v = *(const float4*)(hs_in + (size_t)u * 4);
        s.x += v.x; s.y += v.y; s.z += v.z; s.w += v.w;
    }
#pragma unroll
    for (int off = 8; off >= 1; off >>= 1) {
        s.x += __shfl_xor(s.x, off, 16);
        s.y += __shfl_xor(s.y, off, 16);
        s.z += __shfl_xor(s.z, off, 16);
        s.w += __shfl_xor(s.w, off, 16);
    }
    if (lane == 0) {
        float4 self = *(const float4*)(hs_in + (size_t)node * 4);
        s.x += self.x; s.y += self.y; s.z += self.z; s.w += self.w;
        float dv = dinv[node];
        float h0 = fmaxf(fmaf(dv, s.x, b[0]), 0.f);
        float h1 = fmaxf(fmaf(dv, s.y, b[1]), 0.f);
        float h2 = fmaxf(fmaf(dv, s.z, b[2]), 0.f);
        float h3 = fmaxf(fmaf(dv, s.w, b[3]), 0.f);
        float4 r;
        r.x = dv * (h0 * W[0] + h1 * W[4] + h2 * W[8]  + h3 * W[12]);
        r.y = dv * (h0 * W[1] + h1 * W[5] + h2 * W[9]  + h3 * W[13]);
        r.z = dv * (h0 * W[2] + h1 * W[6] + h2 * W[10] + h3 * W[14]);
        r.w = dv * (h0 * W[3] + h1 * W[7] + h2 * W[11] + h3 * W[15]);
        *(float4*)(hs_out + (size_t)node * 4) = r;
    }
}

// layer 2: agg(hs2) -> relu(dv*agg+b2) @ W3 * dv -> hs3 (4-wide in, 2-wide out)
__global__ __launch_bounds__(TPB) void k_gather_l2(const int* __restrict__ row_ptr,
                                                   const int* __restrict__ deg,
                                                   const int* __restrict__ perm,
                                                   const float* __restrict__ hs_in,
                                                   const float* __restrict__ dinv,
                                                   const float* __restrict__ W,
                                                   const float* __restrict__ b,
                                                   float* __restrict__ hs_out, int n) {
    int node = blockIdx.x * (TPB / 16) + (threadIdx.x >> 4);
    int lane = threadIdx.x & 15;
    if (node >= n) return;
    int start = row_ptr[node];
    int d = deg[node];
    float4 s = make_float4(0.f, 0.f, 0.f, 0.f);
    for (int j = lane; j < d; j += 16) {
        int u = perm[start + j];
        float4 v = *(const float4*)(hs_in + (size_t)u * 4);
        s.x += v.x; s.y += v.y; s.z += v.z; s.w += v.w;
    }
#pragma unroll
    for (int off = 8; off >= 1; off >>= 1) {
        s.x += __shfl_xor(s.x, off, 16);
        s.y += __shfl_xor(s.y, off, 16);
        s.z += __shfl_xor(s.z, off, 16);
        s.w += __shfl_xor(s.w, off, 16);
    }
    if (lane == 0) {
        float4 self = *(const float4*)(hs_in + (size_t)node * 4);
        s.x += self.x; s.y += self.y; s.z += self.z; s.w += self.w;
        float dv = dinv[node];
        float h0 = fmaxf(fmaf(dv, s.x, b[0]), 0.f);
        float h1 = fmaxf(fmaf(dv, s.y, b[1]), 0.f);
        float h2 = fmaxf(fmaf(dv, s.z, b[2]), 0.f);
        float h3 = fmaxf(fmaf(dv, s.w, b[3]), 0.f);
        float2 r;
        r.x = dv * (h0 * W[0] + h1 * W[2] + h2 * W[4] + h3 * W[6]);
        r.y = dv * (h0 * W[1] + h1 * W[3] + h2 * W[5] + h3 * W[7]);
        *(float2*)(hs_out + (size_t)node * 2) = r;
    }
}

// layer 3: agg(hs3) -> out = dv*agg + b3 (2-wide, no relu)
__global__ __launch_bounds__(TPB) void k_gather_l3(const int* __restrict__ row_ptr,
                                                   const int* __restrict__ deg,
                                                   const int* __restrict__ perm,
                                                   const float* __restrict__ hs_in,
                                                   const float* __restrict__ dinv,
                                                   const float* __restrict__ b,
                                                   float* __restrict__ out, int n) {
    int node = blockIdx.x * (TPB / 16) + (threadIdx.x >> 4);
    int lane = threadIdx.x & 15;
    if (node >= n) return;
    int start = row_ptr[node];
    int d = deg[node];
    float2 s = make_float2(0.f, 0.f);
    for (int j = lane; j < d; j += 16) {
        int u = perm[start + j];
        float2 v = *(const float2*)(hs_in + (size_t)u * 2);
        s.x += v.x; s.y += v.y;
    }
#pragma unroll
    for (int off = 8; off >= 1; off >>= 1) {
        s.x += __shfl_xor(s.x, off, 16);
        s.y += __shfl_xor(s.y, off, 16);
    }
    if (lane == 0) {
        float2 self = *(const float2*)(hs_in + (size_t)node * 2);
        s.x += self.x; s.y += self.y;
        float dv = dinv[node];
        float2 o;
        o.x = fmaf(dv, s.x, b[0]);
        o.y = fmaf(dv, s.y, b[1]);
        *(float2*)(out + (size_t)node * 2) = o;
    }
}

// ==================== fallback (round-1 atomic path) ====================

__global__ __launch_bounds__(TPB) void k_degree(const int* __restrict__ dst,
                                                int* __restrict__ deg, int E) {
    int e4 = E >> 2;
    int i = blockIdx.x * TPB + threadIdx.x;
    if (i < e4) {
        int4 d = ((const int4*)dst)[i];
        atomicAdd(&deg[d.x], 1);
        atomicAdd(&deg[d.y], 1);
        atomicAdd(&deg[d.z], 1);
        atomicAdd(&deg[d.w], 1);
    }
    if (i < (E & 3)) atomicAdd(&deg[dst[(e4 << 2) + i]], 1);
}

__global__ __launch_bounds__(TPB) void k_scatter4(const int* __restrict__ src,
                                                  const int* __restrict__ dst,
                                                  const float* __restrict__ hs,
                                                  float* __restrict__ acc, int E) {
    int e4 = E >> 2;
    int i = blockIdx.x * TPB + threadIdx.x;
    if (i < e4) {
        int4 s = ((const int4*)src)[i];
        int4 d = ((const int4*)dst)[i];
        float4 v0 = *(const float4*)(hs + (size_t)s.x * 4);
        float4 v1 = *(const float4*)(hs + (size_t)s.y * 4);
        float4 v2 = *(const float4*)(hs + (size_t)s.z * 4);
        float4 v3 = *(const float4*)(hs + (size_t)s.w * 4);
        float* a;
        a = acc + (size_t)d.x * 4;
        atomAddF(a + 0, v0.x); atomAddF(a + 1, v0.y); atomAddF(a + 2, v0.z); atomAddF(a + 3, v0.w);
        a = acc + (size_t)d.y * 4;
        atomAddF(a + 0, v1.x); atomAddF(a + 1, v1.y); atomAddF(a + 2, v1.z); atomAddF(a + 3, v1.w);
        a = acc + (size_t)d.z * 4;
        atomAddF(a + 0, v2.x); atomAddF(a + 1, v2.y); atomAddF(a + 2, v2.z); atomAddF(a + 3, v2.w);
        a = acc + (size_t)d.w * 4;
        atomAddF(a + 0, v3.x); atomAddF(a + 1, v3.y); atomAddF(a + 2, v3.z); atomAddF(a + 3, v3.w);
    }
    if (i < (E & 3)) {
        int e = (e4 << 2) + i;
        int s = src[e], d = dst[e];
        float4 v = *(const float4*)(hs + (size_t)s * 4);
        float* a = acc + (size_t)d * 4;
        atomAddF(a + 0, v.x); atomAddF(a + 1, v.y); atomAddF(a + 2, v.z); atomAddF(a + 3, v.w);
    }
}

__global__ __launch_bounds__(TPB) void k_scatter2(const int* __restrict__ src,
                                                  const int* __restrict__ dst,
                                                  const float* __restrict__ hs,
                                                  float* __restrict__ acc, int E) {
    int e4 = E >> 2;
    int i = blockIdx.x * TPB + threadIdx.x;
    if (i < e4) {
        int4 s = ((const int4*)src)[i];
        int4 d = ((const int4*)dst)[i];
        float2 v0 = *(const float2*)(hs + (size_t)s.x * 2);
        float2 v1 = *(const float2*)(hs + (size_t)s.y * 2);
        float2 v2 = *(const float2*)(hs + (size_t)s.z * 2);
        float2 v3 = *(const float2*)(hs + (size_t)s.w * 2);
        float* a;
        a = acc + (size_t)d.x * 2; atomAddF(a + 0, v0.x); atomAddF(a + 1, v0.y);
        a = acc + (size_t)d.y * 2; atomAddF(a + 0, v1.x); atomAddF(a + 1, v1.y);
        a = acc + (size_t)d.z * 2; atomAddF(a + 0, v2.x); atomAddF(a + 1, v2.y);
        a = acc + (size_t)d.w * 2; atomAddF(a + 0, v3.x); atomAddF(a + 1, v3.y);
    }
    if (i < (E & 3)) {
        int e = (e4 << 2) + i;
        int s = src[e], d = dst[e];
        float2 v = *(const float2*)(hs + (size_t)s * 2);
        float* a = acc + (size_t)d * 2;
        atomAddF(a + 0, v.x); atomAddF(a + 1, v.y);
    }
}

__global__ __launch_bounds__(TPB) void k_xform1_acc(const float* __restrict__ x,
                                                    const float* __restrict__ W,
                                                    const float* __restrict__ dinv,
                                                    float* __restrict__ hs,
                                                    float* __restrict__ acc, int n) {
    int node = blockIdx.x * (TPB / 32) + (threadIdx.x >> 5);
    int lane = threadIdx.x & 31;
    if (node >= n) return;
    int k = lane * 4;
    float4 xv = *(const float4*)(x + (size_t)node * 128 + k);
    float4 w0 = *(const float4*)(W + (size_t)(k + 0) * 4);
    float4 w1 = *(const float4*)(W + (size_t)(k + 1) * 4);
    float4 w2 = *(const float4*)(W + (size_t)(k + 2) * 4);
    float4 w3 = *(const float4*)(W + (size_t)(k + 3) * 4);
    float p0 = xv.x * w0.x + xv.y * w1.x + xv.z * w2.x + xv.w * w3.x;
    float p1 = xv.x * w0.y + xv.y * w1.y + xv.z * w2.y + xv.w * w3.y;
    float p2 = xv.x * w0.z + xv.y * w1.z + xv.z * w2.z + xv.w * w3.z;
    float p3 = xv.x * w0.w + xv.y * w1.w + xv.z * w2.w + xv.w * w3.w;
#pragma unroll
    for (int off = 16; off >= 1; off >>= 1) {
        p0 += __shfl_down(p0, off, 32);
        p1 += __shfl_down(p1, off, 32);
        p2 += __shfl_down(p2, off, 32);
        p3 += __shfl_down(p3, off, 32);
    }
    if (lane == 0) {
        float dv = dinv[node];
        float4 r = make_float4(dv * p0, dv * p1, dv * p2, dv * p3);
        *(float4*)(hs + (size_t)node * 4)  = r;
        *(float4*)(acc + (size_t)node * 4) = r;
    }
}

__global__ __launch_bounds__(TPB) void k_xform2(const float* __restrict__ acc_in,
                                                const float* __restrict__ dinv,
                                                const float* __restrict__ W,
                                                const float* __restrict__ b,
                                                float* __restrict__ hs,
                                                float* __restrict__ acc, int n) {
    int i = blockIdx.x * TPB + threadIdx.x;
    if (i >= n) return;
    float dv = dinv[i];
    float4 a = *(const float4*)(acc_in + (size_t)i * 4);
    float h0 = fmaxf(fmaf(dv, a.x, b[0]), 0.f);
    float h1 = fmaxf(fmaf(dv, a.y, b[1]), 0.f);
    float h2 = fmaxf(fmaf(dv, a.z, b[2]), 0.f);
    float h3 = fmaxf(fmaf(dv, a.w, b[3]), 0.f);
    float4 r;
    r.x = dv * (h0 * W[0] + h1 * W[4] + h2 * W[8]  + h3 * W[12]);
    r.y = dv * (h0 * W[1] + h1 * W[5] + h2 * W[9]  + h3 * W[13]);
    r.z = dv * (h0 * W[2] + h1 * W[6] + h2 * W[10] + h3 * W[14]);
    r.w = dv * (h0 * W[3] + h1 * W[7] + h2 * W[11] + h3 * W[15]);
    *(float4*)(hs + (size_t)i * 4)  = r;
    *(float4*)(acc + (size_t)i * 4) = r;
}

__global__ __launch_bounds__(TPB) void k_xform3(const float* __restrict__ acc_in,
                                                const float* __restrict__ dinv,
                                                const float* __restrict__ W,
                                                const float* __restrict__ b,
                                                float* __restrict__ hs,
                                                float* __restrict__ acc, int n) {
    int i = blockIdx.x * TPB + threadIdx.x;
    if (i >= n) return;
    float dv = dinv[i];
    float4 a = *(const float4*)(acc_in + (size_t)i * 4);
    float h0 = fmaxf(fmaf(dv, a.x, b[0]), 0.f);
    float h1 = fmaxf(fmaf(dv, a.y, b[1]), 0.f);
    float h2 = fmaxf(fmaf(dv, a.z, b[2]), 0.f);
    float h3 = fmaxf(fmaf(dv, a.w, b[3]), 0.f);
    float2 r;
    r.x = dv * (h0 * W[0] + h1 * W[2] + h2 * W[4] + h3 * W[6]);
    r.y = dv * (h0 * W[1] + h1 * W[3] + h2 * W[5] + h3 * W[7]);
    *(float2*)(hs + (size_t)i * 2)  = r;
    *(float2*)(acc + (size_t)i * 2) = r;
}

__global__ __launch_bounds__(TPB) void k_final(const float* __restrict__ acc_in,
                                               const float* __restrict__ dinv,
                                               const float* __restrict__ b,
                                               float* __restrict__ out, int n) {
    int i = blockIdx.x * TPB + threadIdx.x;
    if (i >= n) return;
    float dv = dinv[i];
    float2 a = *(const float2*)(acc_in + (size_t)i * 2);
    float2 o;
    o.x = fmaf(dv, a.x, b[0]);
    o.y = fmaf(dv, a.y, b[1]);
    *(float2*)(out + (size_t)i * 2) = o;
}

// ============================ launch ============================

extern "C" void kernel_launch(void* const* d_in, const int* in_sizes, int n_in,
                              void* d_out, int out_size, void* d_ws, size_t ws_size,
                              hipStream_t stream) {
    const float* x  = (const float*)d_in[0];
    const int*   ei = (const int*)d_in[1];
    const float* W1 = (const float*)d_in[2];
    const float* b1 = (const float*)d_in[3];
    const float* W2 = (const float*)d_in[4];
    const float* b2 = (const float*)d_in[5];
    const float* W3 = (const float*)d_in[6];
    const float* b3 = (const float*)d_in[7];
    float* out = (float*)d_out;

    const int n = in_sizes[0] / 128;   // 500000
    const int E = in_sizes[1] / 2;     // 16000000
    const int* src = ei;
    const int* dst = ei + E;
    (void)n_in; (void)out_size;

    char* ws = (char*)d_ws;
    size_t off = 0;
    auto alloc = [&](size_t bytes) -> char* {
        char* p = ws + off;
        off += (bytes + 255) & ~(size_t)255;
        return p;
    };

    int e4 = E >> 2;
    int gridE  = (e4 > 0 ? (e4 + TPB - 1) / TPB : 1);
    int gridN  = (n + TPB - 1) / TPB;
    int gridX1 = (n + (TPB / 32) - 1) / (TPB / 32);
    int gridG  = (n + (TPB / 16) - 1) / (TPB / 16);
    int nScanBlocks = (n + SCAN_CHUNK - 1) / SCAN_CHUNK;

    // CSR path workspace requirement
    size_t need = 0;
    {
        size_t t = 0;
        auto acct = [&](size_t bytes) { t += (bytes + 255) & ~(size_t)255; };
        acct((size_t)n * 4);           // cnt/deg
        acct((size_t)n * 4);           // row_ptr
        acct((size_t)n * 4);           // dinv
        acct((size_t)n * 16);          // hs1
        acct((size_t)n * 16);          // hs2
        acct((size_t)n * 8);           // hs3
        acct((size_t)E * 4);           // pos
        acct((size_t)E * 4);           // perm
        acct((size_t)nScanBlocks * 4); // blockSums
        acct(256);                     // dummy
        need = t;
    }

    if (ws_size >= need) {
        // ======== CSR gather path ========
        int*   deg     = (int*)  alloc((size_t)n * 4);
        int*   row_ptr = (int*)  alloc((size_t)n * 4);
        float* dinv    = (float*)alloc((size_t)n * 4);
        float* hs1     = (float*)alloc((size_t)n * 16);
        float* hs2     = (float*)alloc((size_t)n * 16);
        float* hs3     = (float*)alloc((size_t)n * 8);
        int*   pos     = (int*)  alloc((size_t)E * 4);
        int*   perm    = (int*)  alloc((size_t)E * 4);
        int*   bsums   = (int*)  alloc((size_t)nScanBlocks * 4);
        int*   dummy   = (int*)  alloc(256);

        hipMemsetAsync(deg, 0, (size_t)n * 4, stream);

        k_binpos<<<gridE, TPB, 0, stream>>>(dst, deg, pos, E);
        k_scan_block<<<nScanBlocks, TPB, 0, stream>>>(deg, row_ptr, bsums, n);
        k_scan_block<<<1, TPB, 0, stream>>>(bsums, bsums, dummy, nScanBlocks);
        k_scan_add<<<gridN, TPB, 0, stream>>>(row_ptr, bsums, n);
        k_binfill<<<gridE, TPB, 0, stream>>>(src, dst, pos, row_ptr, perm, E);
        k_dinv<<<gridN, TPB, 0, stream>>>(deg, dinv, n);

        k_xform1<<<gridX1, TPB, 0, stream>>>(x, W1, dinv, hs1, n);
        k_gather_l1<<<gridG, TPB, 0, stream>>>(row_ptr, deg, perm, hs1, dinv, W2, b1, hs2, n);
        k_gather_l2<<<gridG, TPB, 0, stream>>>(row_ptr, deg, perm, hs2, dinv, W3, b2, hs3, n);
        k_gather_l3<<<gridG, TPB, 0, stream>>>(row_ptr, deg, perm, hs3, dinv, b3, out, n);
    } else {
        // ======== fallback: round-1 atomic scatter path ========
        int*   deg  = (int*)  alloc((size_t)n * 4);
        float* dinv = (float*)alloc((size_t)n * 4);
        float* hs1  = (float*)alloc((size_t)n * 16);
        float* acc1 = (float*)alloc((size_t)n * 16);
        float* hs2  = (float*)alloc((size_t)n * 16);
        float* acc2 = (float*)alloc((size_t)n * 16);
        float* hs3  = (float*)alloc((size_t)n * 8);
        float* acc3 = (float*)alloc((size_t)n * 8);

        hipMemsetAsync(deg, 0, (size_t)n * 4, stream);

        k_degree<<<gridE, TPB, 0, stream>>>(dst, deg, E);
        k_dinv<<<gridN, TPB, 0, stream>>>(deg, dinv, n);

        k_xform1_acc<<<gridX1, TPB, 0, stream>>>(x, W1, dinv, hs1, acc1, n);
        k_scatter4<<<gridE, TPB, 0, stream>>>(src, dst, hs1, acc1, E);
        k_xform2<<<gridN, TPB, 0, stream>>>(acc1, dinv, W2, b1, hs2, acc2, n);
        k_scatter4<<<gridE, TPB, 0, stream>>>(src, dst, hs2, acc2, E);
        k_xform3<<<gridN, TPB, 0, stream>>>(acc2, dinv, W3, b2, hs3, acc3, n);
        k_scatter2<<<gridE, TPB, 0, stream>>>(src, dst, hs3, acc3, E);
        k_final<<<gridN, TPB, 0, stream>>>(acc3, dinv, b3, out, n);
    }
}

// Round 3
// 1390.061 us; speedup vs baseline: 6.3611x; 1.3781x over previous
//
#include <hip/hip_runtime.h>

#define TPB 256
#define BUCKET_BITS 9
#define BUCKET_SZ   (1 << BUCKET_BITS)       // 512 nodes per dst-bucket
#define SRC_BITS    19                        // packed path requires n <= 2^19
#define SRC_MASK    ((1u << SRC_BITS) - 1u)
#define NB_MAX      1024                      // LDS histogram capacity
#define CHUNK       16384                     // edges per partition block
#define SCAN_CHUNK  2048

// ============================ dense transform ============================

// ---- layer 1 transform: hs = dinv * (x @ W1) ----
__global__ __launch_bounds__(TPB) void k_xform1(const float* __restrict__ x,
                                                const float* __restrict__ W,
                                                const float* __restrict__ dinv,
                                                float* __restrict__ hs, int n) {
    int node = blockIdx.x * (TPB / 32) + (threadIdx.x >> 5);
    int lane = threadIdx.x & 31;
    if (node >= n) return;
    int k = lane * 4;
    float4 xv = *(const float4*)(x + (size_t)node * 128 + k);
    float4 w0 = *(const float4*)(W + (size_t)(k + 0) * 4);
    float4 w1 = *(const float4*)(W + (size_t)(k + 1) * 4);
    float4 w2 = *(const float4*)(W + (size_t)(k + 2) * 4);
    float4 w3 = *(const float4*)(W + (size_t)(k + 3) * 4);
    float p0 = xv.x * w0.x + xv.y * w1.x + xv.z * w2.x + xv.w * w3.x;
    float p1 = xv.x * w0.y + xv.y * w1.y + xv.z * w2.y + xv.w * w3.y;
    float p2 = xv.x * w0.z + xv.y * w1.z + xv.z * w2.z + xv.w * w3.z;
    float p3 = xv.x * w0.w + xv.y * w1.w + xv.z * w2.w + xv.w * w3.w;
#pragma unroll
    for (int off = 16; off >= 1; off >>= 1) {
        p0 += __shfl_down(p0, off, 32);
        p1 += __shfl_down(p1, off, 32);
        p2 += __shfl_down(p2, off, 32);
        p3 += __shfl_down(p3, off, 32);
    }
    if (lane == 0) {
        float dv = dinv[node];
        *(float4*)(hs + (size_t)node * 4) = make_float4(dv * p0, dv * p1, dv * p2, dv * p3);
    }
}

// ============================ scan (two-level) ============================

__global__ __launch_bounds__(TPB) void k_scan_block(const int* __restrict__ in,
                                                    int* __restrict__ out,
                                                    int* __restrict__ blockSums, int n) {
    __shared__ int waveTot[TPB / 64];
    int base = blockIdx.x * SCAN_CHUNK + threadIdx.x * 8;
    int v[8];
    int s = 0;
#pragma unroll
    for (int j = 0; j < 8; j++) {
        int idx = base + j;
        int xval = (idx < n) ? in[idx] : 0;
        v[j] = s;
        s += xval;
    }
    int lane = threadIdx.x & 63, wave = threadIdx.x >> 6;
    int t = s;
#pragma unroll
    for (int off = 1; off < 64; off <<= 1) {
        int u = __shfl_up(t, off, 64);
        if (lane >= off) t += u;
    }
    if (lane == 63) waveTot[wave] = t;
    __syncthreads();
    int waveOff = 0;
    for (int w = 0; w < wave; w++) waveOff += waveTot[w];
    int myStart = waveOff + (t - s);
#pragma unroll
    for (int j = 0; j < 8; j++) {
        int idx = base + j;
        if (idx < n) out[idx] = myStart + v[j];
    }
    if (threadIdx.x == TPB - 1) blockSums[blockIdx.x] = waveOff + t;
}

__global__ __launch_bounds__(TPB) void k_scan_add(int* __restrict__ out,
                                                  const int* __restrict__ blockSums, int n) {
    int i = blockIdx.x * TPB + threadIdx.x;
    if (i >= n) return;
    out[i] += blockSums[i / SCAN_CHUNK];
}

// ===================== counting-sort CSR build (no global atomics) =====================

// per-chunk LDS histogram over dst buckets; hist laid out [bucket][chunk]
__global__ __launch_bounds__(TPB) void k_hist(const int* __restrict__ dst, int E,
                                              int* __restrict__ hist,
                                              int NB, int nChunks) {
    __shared__ int h[NB_MAX];
    for (int j = threadIdx.x; j < NB_MAX; j += TPB) h[j] = 0;
    __syncthreads();
    int base = blockIdx.x * CHUNK;
    for (int i = threadIdx.x; i < CHUNK; i += TPB) {
        int e = base + i;
        if (e < E) atomicAdd(&h[dst[e] >> BUCKET_BITS], 1);
    }
    __syncthreads();
    for (int j = threadIdx.x; j < NB; j += TPB)
        hist[(size_t)j * nChunks + blockIdx.x] = h[j];
}

// scatter packed (localDst<<19 | src) into scanned per-(bucket,chunk) ranges
__global__ __launch_bounds__(TPB) void k_part(const int* __restrict__ src,
                                              const int* __restrict__ dst, int E,
                                              const int* __restrict__ scanned,
                                              unsigned* __restrict__ packed,
                                              int NB, int nChunks) {
    __shared__ int offs[NB_MAX];
    for (int j = threadIdx.x; j < NB; j += TPB)
        offs[j] = scanned[(size_t)j * nChunks + blockIdx.x];
    __syncthreads();
    int base = blockIdx.x * CHUNK;
    for (int i = threadIdx.x; i < CHUNK; i += TPB) {
        int e = base + i;
        if (e >= E) break;
        int s = src[e];
        int d = dst[e];
        int b = d >> BUCKET_BITS;
        int p = atomicAdd(&offs[b], 1);
        packed[p] = ((unsigned)(d & (BUCKET_SZ - 1)) << SRC_BITS) | (unsigned)s;
    }
}

// one block per bucket: local count + scan -> row_ptr/deg/dinv + perm fill
__global__ __launch_bounds__(TPB) void k_csr(const unsigned* __restrict__ packed,
                                             const int* __restrict__ scanned,
                                             int E, int n, int NB, int nChunks,
                                             int* __restrict__ row,
                                             int* __restrict__ deg,
                                             float* __restrict__ dinv,
                                             int* __restrict__ perm) {
    __shared__ int cnt[BUCKET_SZ];
    __shared__ int off_[BUCKET_SZ];
    __shared__ int waveTot[TPB / 64];
    int b = blockIdx.x;
    int tid = threadIdx.x;
    int base = b << BUCKET_BITS;
    int nNodes = min(BUCKET_SZ, n - base);
    int bucketStart = scanned[(size_t)b * nChunks];
    int bucketEnd = (b + 1 < NB) ? scanned[(size_t)(b + 1) * nChunks] : E;

    cnt[tid] = 0; cnt[tid + TPB] = 0;
    __syncthreads();
    for (int i = bucketStart + tid; i < bucketEnd; i += TPB)
        atomicAdd(&cnt[packed[i] >> SRC_BITS], 1);
    __syncthreads();

    // exclusive scan of cnt[0..511]; 2 elems/thread
    int v0 = cnt[2 * tid], v1 = cnt[2 * tid + 1];
    int s = v0 + v1;
    int lane = tid & 63, wave = tid >> 6;
    int t = s;
#pragma unroll
    for (int o = 1; o < 64; o <<= 1) {
        int u = __shfl_up(t, o, 64);
        if (lane >= o) t += u;
    }
    if (lane == 63) waveTot[wave] = t;
    __syncthreads();
    int wOff = 0;
    for (int w = 0; w < wave; w++) wOff += waveTot[w];
    int ex = wOff + (t - s);
    off_[2 * tid] = ex;
    off_[2 * tid + 1] = ex + v0;
    __syncthreads();

    for (int j = tid; j < nNodes; j += TPB) {
        int c = cnt[j];
        deg[base + j] = c;
        row[base + j] = bucketStart + off_[j];
        dinv[base + j] = rsqrtf((float)(c + 1));
    }
    __syncthreads();

    for (int i = bucketStart + tid; i < bucketEnd; i += TPB) {
        unsigned u = packed[i];
        int ld = (int)(u >> SRC_BITS);
        int p = atomicAdd(&off_[ld], 1);
        perm[bucketStart + p] = (int)(u & SRC_MASK);
    }
}

// ============================ fused gather layers ============================

__global__ __launch_bounds__(TPB) void k_gather_l1(const int* __restrict__ row_ptr,
                                                   const int* __restrict__ deg,
                                                   const int* __restrict__ perm,
                                                   const float* __restrict__ hs_in,
                                                   const float* __restrict__ dinv,
                                                   const float* __restrict__ W,
                                                   const float* __restrict__ b,
                                                   float* __restrict__ hs_out, int n) {
    int node = blockIdx.x * (TPB / 16) + (threadIdx.x >> 4);
    int lane = threadIdx.x & 15;
    if (node >= n) return;
    int start = row_ptr[node];
    int d = deg[node];
    float4 s = make_float4(0.f, 0.f, 0.f, 0.f);
    for (int j = lane; j < d; j += 16) {
        int u = perm[start + j];
        float4 v = *(const float4*)(hs_in + (size_t)u * 4);
        s.x += v.x; s.y += v.y; s.z += v.z; s.w += v.w;
    }
#pragma unroll
    for (int off = 8; off >= 1; off >>= 1) {
        s.x += __shfl_xor(s.x, off, 16);
        s.y += __shfl_xor(s.y, off, 16);
        s.z += __shfl_xor(s.z, off, 16);
        s.w += __shfl_xor(s.w, off, 16);
    }
    if (lane == 0) {
        float4 self = *(const float4*)(hs_in + (size_t)node * 4);
        s.x += self.x; s.y += self.y; s.z += self.z; s.w += self.w;
        float dv = dinv[node];
        float h0 = fmaxf(fmaf(dv, s.x, b[0]), 0.f);
        float h1 = fmaxf(fmaf(dv, s.y, b[1]), 0.f);
        float h2 = fmaxf(fmaf(dv, s.z, b[2]), 0.f);
        float h3 = fmaxf(fmaf(dv, s.w, b[3]), 0.f);
        float4 r;
        r.x = dv * (h0 * W[0] + h1 * W[4] + h2 * W[8]  + h3 * W[12]);
        r.y = dv * (h0 * W[1] + h1 * W[5] + h2 * W[9]  + h3 * W[13]);
        r.z = dv * (h0 * W[2] + h1 * W[6] + h2 * W[10] + h3 * W[14]);
        r.w = dv * (h0 * W[3] + h1 * W[7] + h2 * W[11] + h3 * W[15]);
        *(float4*)(hs_out + (size_t)node * 4) = r;
    }
}

__global__ __launch_bounds__(TPB) void k_gather_l2(const int* __restrict__ row_ptr,
                                                   const int* __restrict__ deg,
                                                   const int* __restrict__ perm,
                                                   const float* __restrict__ hs_in,
                                                   const float* __restrict__ dinv,
                                                   const float* __restrict__ W,
                                                   const float* __restrict__ b,
                                                   float* __restrict__ hs_out, int n) {
    int node = blockIdx.x * (TPB / 16) + (threadIdx.x >> 4);
    int lane = threadIdx.x & 15;
    if (node >= n) return;
    int start = row_ptr[node];
    int d = deg[node];
    float4 s = make_float4(0.f, 0.f, 0.f, 0.f);
    for (int j = lane; j < d; j += 16) {
        int u = perm[start + j];
        float4 v = *(const float4*)(hs_in + (size_t)u * 4);
        s.x += v.x; s.y += v.y; s.z += v.z; s.w += v.w;
    }
#pragma unroll
    for (int off = 8; off >= 1; off >>= 1) {
        s.x += __shfl_xor(s.x, off, 16);
        s.y += __shfl_xor(s.y, off, 16);
        s.z += __shfl_xor(s.z, off, 16);
        s.w += __shfl_xor(s.w, off, 16);
    }
    if (lane == 0) {
        float4 self = *(const float4*)(hs_in + (size_t)node * 4);
        s.x += self.x; s.y += self.y; s.z += self.z; s.w += self.w;
        float dv = dinv[node];
        float h0 = fmaxf(fmaf(dv, s.x, b[0]), 0.f);
        float h1 = fmaxf(fmaf(dv, s.y, b[1]), 0.f);
        float h2 = fmaxf(fmaf(dv, s.z, b[2]), 0.f);
        float h3 = fmaxf(fmaf(dv, s.w, b[3]), 0.f);
        float2 r;
        r.x = dv * (h0 * W[0] + h1 * W[2] + h2 * W[4] + h3 * W[6]);
        r.y = dv * (h0 * W[1] + h1 * W[3] + h2 * W[5] + h3 * W[7]);
        *(float2*)(hs_out + (size_t)node * 2) = r;
    }
}

__global__ __launch_bounds__(TPB) void k_gather_l3(const int* __restrict__ row_ptr,
                                                   const int* __restrict__ deg,
                                                   const int* __restrict__ perm,
                                                   const float* __restrict__ hs_in,
                                                   const float* __restrict__ dinv,
                                                   const float* __restrict__ b,
                                                   float* __restrict__ out, int n) {
    int node = blockIdx.x * (TPB / 16) + (threadIdx.x >> 4);
    int lane = threadIdx.x & 15;
    if (node >= n) return;
    int start = row_ptr[node];
    int d = deg[node];
    float2 s = make_float2(0.f, 0.f);
    for (int j = lane; j < d; j += 16) {
        int u = perm[start + j];
        float2 v = *(const float2*)(hs_in + (size_t)u * 2);
        s.x += v.x; s.y += v.y;
    }
#pragma unroll
    for (int off = 8; off >= 1; off >>= 1) {
        s.x += __shfl_xor(s.x, off, 16);
        s.y += __shfl_xor(s.y, off, 16);
    }
    if (lane == 0) {
        float2 self = *(const float2*)(hs_in + (size_t)node * 2);
        s.x += self.x; s.y += self.y;
        float dv = dinv[node];
        float2 o;
        o.x = fmaf(dv, s.x, b[0]);
        o.y = fmaf(dv, s.y, b[1]);
        *(float2*)(out + (size_t)node * 2) = o;
    }
}

// ==================== fallback CSR build (round-2 atomic path) ====================

__global__ __launch_bounds__(TPB) void k_binpos(const int* __restrict__ dst,
                                                int* __restrict__ cnt,
                                                int* __restrict__ pos, int E) {
    int e4 = E >> 2;
    int i = blockIdx.x * TPB + threadIdx.x;
    if (i < e4) {
        int4 d = ((const int4*)dst)[i];
        int4 p;
        p.x = atomicAdd(&cnt[d.x], 1);
        p.y = atomicAdd(&cnt[d.y], 1);
        p.z = atomicAdd(&cnt[d.z], 1);
        p.w = atomicAdd(&cnt[d.w], 1);
        ((int4*)pos)[i] = p;
    }
    if (i < (E & 3)) {
        int e = (e4 << 2) + i;
        pos[e] = atomicAdd(&cnt[dst[e]], 1);
    }
}

__global__ __launch_bounds__(TPB) void k_binfill(const int* __restrict__ src,
                                                 const int* __restrict__ dst,
                                                 const int* __restrict__ pos,
                                                 const int* __restrict__ row_ptr,
                                                 int* __restrict__ perm, int E) {
    int e4 = E >> 2;
    int i = blockIdx.x * TPB + threadIdx.x;
    if (i < e4) {
        int4 s = ((const int4*)src)[i];
        int4 d = ((const int4*)dst)[i];
        int4 p = ((const int4*)pos)[i];
        perm[row_ptr[d.x] + p.x] = s.x;
        perm[row_ptr[d.y] + p.y] = s.y;
        perm[row_ptr[d.z] + p.z] = s.z;
        perm[row_ptr[d.w] + p.w] = s.w;
    }
    if (i < (E & 3)) {
        int e = (e4 << 2) + i;
        perm[row_ptr[dst[e]] + pos[e]] = src[e];
    }
}

__global__ __launch_bounds__(TPB) void k_dinv(const int* __restrict__ deg,
                                              float* __restrict__ dinv, int n) {
    int i = blockIdx.x * TPB + threadIdx.x;
    if (i >= n) return;
    dinv[i] = rsqrtf((float)(deg[i] + 1));
}

// ============================ launch ============================

extern "C" void kernel_launch(void* const* d_in, const int* in_sizes, int n_in,
                              void* d_out, int out_size, void* d_ws, size_t ws_size,
                              hipStream_t stream) {
    const float* x  = (const float*)d_in[0];
    const int*   ei = (const int*)d_in[1];
    const float* W1 = (const float*)d_in[2];
    const float* b1 = (const float*)d_in[3];
    const float* W2 = (const float*)d_in[4];
    const float* b2 = (const float*)d_in[5];
    const float* W3 = (const float*)d_in[6];
    const float* b3 = (const float*)d_in[7];
    float* out = (float*)d_out;

    const int n = in_sizes[0] / 128;   // 500000
    const int E = in_sizes[1] / 2;     // 16000000
    const int* src = ei;
    const int* dst = ei + E;
    (void)n_in; (void)out_size;

    char* ws = (char*)d_ws;
    size_t off = 0;
    auto alloc = [&](size_t bytes) -> char* {
        char* p = ws + off;
        off += (bytes + 255) & ~(size_t)255;
        return p;
    };

    const int NB = (n + BUCKET_SZ - 1) >> BUCKET_BITS;            // 977
    const int nChunks = (E + CHUNK - 1) / CHUNK;                  // 977
    const size_t histN = (size_t)NB * nChunks;                    // ~955k
    const int nScanBlocksH = (int)((histN + SCAN_CHUNK - 1) / SCAN_CHUNK);

    int gridN  = (n + TPB - 1) / TPB;
    int gridX1 = (n + (TPB / 32) - 1) / (TPB / 32);
    int gridG  = (n + (TPB / 16) - 1) / (TPB / 16);

    // packed-path workspace requirement
    size_t need = 0;
    {
        size_t t = 0;
        auto acct = [&](size_t bytes) { t += (bytes + 255) & ~(size_t)255; };
        acct((size_t)n * 4);            // deg
        acct((size_t)n * 4);            // row
        acct((size_t)n * 4);            // dinv
        acct((size_t)n * 16);           // hs1
        acct((size_t)n * 16);           // hs2
        acct((size_t)n * 8);            // hs3
        acct((size_t)E * 4);            // packed
        acct((size_t)E * 4);            // perm
        acct(histN * 4);                // hist
        acct((size_t)nScanBlocksH * 4); // bsums
        acct(256);                      // dummy
        need = t;
    }

    bool packedOK = (n <= (1 << SRC_BITS)) && (NB <= NB_MAX) &&
                    (nScanBlocksH <= SCAN_CHUNK) && (ws_size >= need);

    if (packedOK) {
        int*      deg    = (int*)  alloc((size_t)n * 4);
        int*      row    = (int*)  alloc((size_t)n * 4);
        float*    dinv   = (float*)alloc((size_t)n * 4);
        float*    hs1    = (float*)alloc((size_t)n * 16);
        float*    hs2    = (float*)alloc((size_t)n * 16);
        float*    hs3    = (float*)alloc((size_t)n * 8);
        unsigned* packed = (unsigned*)alloc((size_t)E * 4);
        int*      perm   = (int*)  alloc((size_t)E * 4);
        int*      hist   = (int*)  alloc(histN * 4);
        int*      bsums  = (int*)  alloc((size_t)nScanBlocksH * 4);
        int*      dummy  = (int*)  alloc(256);

        // build CSR (no global atomics anywhere)
        k_hist<<<nChunks, TPB, 0, stream>>>(dst, E, hist, NB, nChunks);
        k_scan_block<<<nScanBlocksH, TPB, 0, stream>>>(hist, hist, bsums, (int)histN);
        k_scan_block<<<1, TPB, 0, stream>>>(bsums, bsums, dummy, nScanBlocksH);
        k_scan_add<<<(int)((histN + TPB - 1) / TPB), TPB, 0, stream>>>(hist, bsums, (int)histN);
        k_part<<<nChunks, TPB, 0, stream>>>(src, dst, E, hist, packed, NB, nChunks);
        k_csr<<<NB, TPB, 0, stream>>>(packed, hist, E, n, NB, nChunks, row, deg, dinv, perm);

        // layers
        k_xform1<<<gridX1, TPB, 0, stream>>>(x, W1, dinv, hs1, n);
        k_gather_l1<<<gridG, TPB, 0, stream>>>(row, deg, perm, hs1, dinv, W2, b1, hs2, n);
        k_gather_l2<<<gridG, TPB, 0, stream>>>(row, deg, perm, hs2, dinv, W3, b2, hs3, n);
        k_gather_l3<<<gridG, TPB, 0, stream>>>(row, deg, perm, hs3, dinv, b3, out, n);
    } else {
        // fallback: round-2 global-atomic CSR build
        int e4 = E >> 2;
        int gridE = (e4 > 0 ? (e4 + TPB - 1) / TPB : 1);
        int nScanBlocksN = (n + SCAN_CHUNK - 1) / SCAN_CHUNK;

        int*   deg     = (int*)  alloc((size_t)n * 4);
        int*   row_ptr = (int*)  alloc((size_t)n * 4);
        float* dinv    = (float*)alloc((size_t)n * 4);
        float* hs1     = (float*)alloc((size_t)n * 16);
        float* hs2     = (float*)alloc((size_t)n * 16);
        float* hs3     = (float*)alloc((size_t)n * 8);
        int*   pos     = (int*)  alloc((size_t)E * 4);
        int*   perm    = (int*)  alloc((size_t)E * 4);
        int*   bsums   = (int*)  alloc((size_t)nScanBlocksN * 4);
        int*   dummy   = (int*)  alloc(256);

        hipMemsetAsync(deg, 0, (size_t)n * 4, stream);

        k_binpos<<<gridE, TPB, 0, stream>>>(dst, deg, pos, E);
        k_scan_block<<<nScanBlocksN, TPB, 0, stream>>>(deg, row_ptr, bsums, n);
        k_scan_block<<<1, TPB, 0, stream>>>(bsums, bsums, dummy, nScanBlocksN);
        k_scan_add<<<gridN, TPB, 0, stream>>>(row_ptr, bsums, n);
        k_binfill<<<gridE, TPB, 0, stream>>>(src, dst, pos, row_ptr, perm, E);
        k_dinv<<<gridN, TPB, 0, stream>>>(deg, dinv, n);

        k_xform1<<<gridX1, TPB, 0, stream>>>(x, W1, dinv, hs1, n);
        k_gather_l1<<<gridG, TPB, 0, stream>>>(row_ptr, deg, perm, hs1, dinv, W2, b1, hs2, n);
        k_gather_l2<<<gridG, TPB, 0, stream>>>(row_ptr, deg, perm, hs2, dinv, W3, b2, hs3, n);
        k_gather_l3<<<gridG, TPB, 0, stream>>>(row_ptr, deg, perm, hs3, dinv, b3, out, n);
    }
}